// Round 7
// baseline (113.684 us; speedup 1.0000x reference)
//
#include <hip/hip_runtime.h>
#include <hip/hip_bf16.h>
#include <float.h>

// FactoredQuantizer: B=8192, M=16, N=256, C=64
// inputs  [B, M, C] fp32;  codebook [M, N, C] fp32
// out = codes [B, M, C] fp32 ++ idx [B, M] (as fp32 values)
//
// Round 16: B-reuse doubling on top of round-15's free-running structure
// (which cut main 51 -> ~43 us). Static pipe accounting says the CU-shared
// LDS pipe is now the top consumer (3072 ds_read_b128/CU ~ 15 us): every
// wave re-reads the same 96 B-fragments with per-read MFMA reuse of 2.
// This round: 8 waves x 64 rows (2 row-tiles per super-tile, 2 super-tiles)
// so each B batch feeds BOTH row-tiles -> 1536 b128/CU. Register budget
// acc 64 + afr 48 + bfr 16 + carry 16 + misc ~= 176 under
// __launch_bounds__(512,2)'s 256-reg cap -> no spill (r10/r11's failure
// was a 128/170 budget). Still ONE barrier, free-running waves, identical
// MFMA per-chain order / c2 order / tie rules -> bit-identical output.

#define BQ 8192
#define MQ 16
#define NQ 256
#define CQ 64
#define RPB 512       // rows per block (8 waves x 64 rows)

typedef short  shortx8 __attribute__((ext_vector_type(8)));
typedef float  f32x4   __attribute__((ext_vector_type(4)));

#define HI_MASK 0xffff0000u

// Truncation 3-split of two floats a,b packed into three dwords
// (low short = a's bf16, high short = b's bf16). Exact: a0+a1+a2 == a.
__device__ __forceinline__ void split3_pair(float a, float b,
                                            uint& q0, uint& q1, uint& q2) {
    const uint ba = __builtin_bit_cast(uint, a);
    const uint bb = __builtin_bit_cast(uint, b);
    q0 = (ba >> 16) | (bb & HI_MASK);
    const float r1a = a - __builtin_bit_cast(float, ba & HI_MASK);
    const float r1b = b - __builtin_bit_cast(float, bb & HI_MASK);
    const uint c1a = __builtin_bit_cast(uint, r1a);
    const uint c1b = __builtin_bit_cast(uint, r1b);
    q1 = (c1a >> 16) | (c1b & HI_MASK);
    const float r2a = r1a - __builtin_bit_cast(float, c1a & HI_MASK);
    const float r2b = r1b - __builtin_bit_cast(float, c1b & HI_MASK);
    q2 = (__builtin_bit_cast(uint, r2a) >> 16) |
         (__builtin_bit_cast(uint, r2b) & HI_MASK);
}

// ---------------------------------------------------------------------------
// Fused kernel. Grid (16,16) = 256 blocks = 1/CU; block = 512 threads
// (8 waves, 2/SIMD). Phase 1 (once): transcode this m's codebook slice into
// LDS bf16x3 fragments (96 KB, layout as round 14/15) + c2 (prep's exact
// summation order). ONE __syncthreads. Phase 2: wave w free-runs over rows
// [rowB + w*64, +64) as 2 super-tiles of 32 rows x 256 codes; each
// super-tile = 2 row-tiles sharing every B-fragment batch.
// ---------------------------------------------------------------------------
__global__ __launch_bounds__(512, 2) void fq_fused_kernel(
        const float* __restrict__ inputs,
        const float* __restrict__ codebook,
        float* __restrict__ out_codes,
        float* __restrict__ out_idx) {
    const int m    = blockIdx.y;
    const int rowB = blockIdx.x * RPB;
    const int w    = (int)threadIdx.x >> 6;
    const int lane = (int)threadIdx.x & 63;
    const int quad = lane >> 4;
    const int col  = lane & 15;

    __shared__ unsigned short lds_b[96 * 512];   // 96 KB: 96 frags x 64 lanes x 8
    __shared__ float s_c2v[NQ];

    // ---- transcode codebook slice into LDS fragments + c2 (once) ----
    // item (n, kc): n = item>>3, kc = item&7 (kc == lane&7 -> the 8-lane
    // shfl tree reproduces the original prep kernel's c2 order exactly).
    const float* cbm = codebook + (size_t)m * NQ * CQ;
    #pragma unroll
    for (int it = 0; it < 4; ++it) {
        const int item = (int)threadIdx.x + it * 512;
        const int kc = item & 7;
        const int n  = item >> 3;
        const int nt = n >> 4, cc = n & 15;
        const int h = kc >> 2, q = kc & 3;
        const float* src = cbm + (size_t)n * CQ + kc * 8;
        const float4 va = *(const float4*)src;
        const float4 vb = *(const float4*)(src + 4);
        const float el[8] = {va.x, va.y, va.z, va.w, vb.x, vb.y, vb.z, vb.w};

        float s = 0.0f;
        #pragma unroll
        for (int u = 0; u < 8; ++u) s = fmaf(el[u], el[u], s);
        s += __shfl_xor(s, 1, 64);
        s += __shfl_xor(s, 2, 64);
        s += __shfl_xor(s, 4, 64);
        if (kc == 0) s_c2v[n] = s;

        uint p0[4], p1[4], p2[4];
        #pragma unroll
        for (int u = 0; u < 4; ++u)
            split3_pair(el[2 * u], el[2 * u + 1], p0[u], p1[u], p2[u]);
        const int lf = q * 16 + cc;
        #pragma unroll
        for (int j = 0; j < 3; ++j) {
            const uint* p = (j == 0) ? p0 : (j == 1) ? p1 : p2;
            unsigned short* dst =
                &lds_b[(((j << 1) + h) * 16 + nt) * 512 + lf * 8];
            *(uint4*)dst = make_uint4(p[0], p[1], p[2], p[3]);
        }
    }
    __syncthreads();   // the ONLY barrier: B fragments + c2 ready

    // ---- free-running per-wave main loop: 2 super-tiles of 32 rows ----
    #pragma unroll 1
    for (int tt = 0; tt < 2; ++tt) {
        const int row0 = rowB + w * 64 + tt * 32;

        // A-fragments for BOTH row-tiles: direct per-lane global reads.
        // Lane (quad,col) reads x[row0+rt*16+col][h*32+quad*8 .. +8]; the 8
        // lanes sharing a row jointly consume the full 256B row -> every
        // 64B line fully used, no fetch amplification.
        shortx8 afr[3][2][2];   // [i][rt][h]
        #pragma unroll
        for (int rt = 0; rt < 2; ++rt) {
            const float* xb =
                inputs + ((size_t)(row0 + rt * 16 + col) * MQ + m) * CQ;
            #pragma unroll
            for (int h = 0; h < 2; ++h) {
                const float4 va = *(const float4*)(xb + h * 32 + quad * 8);
                const float4 vb = *(const float4*)(xb + h * 32 + quad * 8 + 4);
                const float el[8] = {va.x, va.y, va.z, va.w,
                                     vb.x, vb.y, vb.z, vb.w};
                uint q0[4], q1[4], q2[4];
                #pragma unroll
                for (int u = 0; u < 4; ++u)
                    split3_pair(el[2 * u], el[2 * u + 1], q0[u], q1[u], q2[u]);
                afr[0][rt][h] = __builtin_bit_cast(shortx8,
                    make_uint4(q0[0], q0[1], q0[2], q0[3]));
                afr[1][rt][h] = __builtin_bit_cast(shortx8,
                    make_uint4(q1[0], q1[1], q1[2], q1[3]));
                afr[2][rt][h] = __builtin_bit_cast(shortx8,
                    make_uint4(q2[0], q2[1], q2[2], q2[3]));
            }
        }

        // Two sequential code-half passes; carry (bd,bi) per row-tile.
        float bd0[2][4]; int bi0[2][4];
        #pragma unroll 1
        for (int chh = 0; chh < 2; ++chh) {
            float c2r[8];
            #pragma unroll
            for (int nt = 0; nt < 8; ++nt)
                c2r[nt] = s_c2v[chh * 128 + nt * 16 + col];

            f32x4 acc[2][8];
            #pragma unroll
            for (int rt = 0; rt < 2; ++rt)
                #pragma unroll
                for (int nt = 0; nt < 8; ++nt)
                    acc[rt][nt] = (f32x4){0.f, 0.f, 0.f, 0.f};

            // hot loop: each B batch (8 ds_read_b128) feeds BOTH row-tiles
            #pragma unroll
            for (int h = 0; h < 2; ++h) {
                #pragma unroll
                for (int j = 0; j < 3; ++j) {
                    shortx8 bfr[8];
                    #pragma unroll
                    for (int nt = 0; nt < 8; ++nt)
                        bfr[nt] = *(const shortx8*)
                            &lds_b[(((j << 1) + h) * 16 + chh * 8 + nt) * 512
                                   + lane * 8];
                    #pragma unroll
                    for (int i = 0; i <= 2 - j; ++i) {
                        #pragma unroll
                        for (int nt = 0; nt < 8; ++nt) {
                            acc[0][nt] = __builtin_amdgcn_mfma_f32_16x16x32_bf16(
                                afr[i][0][h], bfr[nt], acc[0][nt], 0, 0, 0);
                            acc[1][nt] = __builtin_amdgcn_mfma_f32_16x16x32_bf16(
                                afr[i][1][h], bfr[nt], acc[1][nt], 0, 0, 0);
                        }
                    }
                }
            }

            // per-pass argmin: d = c2 - 2*xc; lowest n on ties
            #pragma unroll
            for (int rt = 0; rt < 2; ++rt) {
                #pragma unroll
                for (int reg = 0; reg < 4; ++reg) {
                    float bd = FLT_MAX; int bi = 0;
                    #pragma unroll
                    for (int nt = 0; nt < 8; ++nt) {
                        const float d = fmaf(-2.0f, acc[rt][nt][reg], c2r[nt]);
                        if (d < bd) { bd = d; bi = chh * 128 + nt * 16 + col; }
                    }
                    #pragma unroll
                    for (int mask = 1; mask <= 8; mask <<= 1) { // 16 col lanes
                        const float od = __shfl_xor(bd, mask, 64);
                        const int   oi = __shfl_xor(bi, mask, 64);
                        if (od < bd || (od == bd && oi < bi)) { bd = od; bi = oi; }
                    }
                    if (chh == 0) { bd0[rt][reg] = bd; bi0[rt][reg] = bi; }
                    else {
                        // cross-half combine (pass 0 = lower n: ties keep it)
                        if (bd < bd0[rt][reg] ||
                            (bd == bd0[rt][reg] && bi < bi0[rt][reg])) {
                            bd0[rt][reg] = bd; bi0[rt][reg] = bi;
                        }
                    }
                }
            }
        }

        // idx write: lane (quad, col==0) owns rows rt*16 + quad*4 + reg
        if (col == 0) {
            #pragma unroll
            for (int rt = 0; rt < 2; ++rt)
                #pragma unroll
                for (int reg = 0; reg < 4; ++reg)
                    out_idx[(size_t)(row0 + rt * 16 + quad * 4 + reg) * MQ + m] =
                        (float)bi0[rt][reg];
        }

        // gather codes: row jj's winner lives on lane ((jj&15)>>2)*16,
        // reg jj&3 of tile jj>>4; lane = element (256B stores)
        #pragma unroll
        for (int jj = 0; jj < 32; ++jj) {
            const int rt  = jj >> 4;
            const int r16 = jj & 15;
            const int bn  = __shfl(bi0[rt][r16 & 3], (r16 >> 2) * 16, 64);
            out_codes[((size_t)(row0 + jj) * MQ + m) * CQ + lane] =
                cbm[(size_t)bn * CQ + lane];
        }
    }
}

extern "C" void kernel_launch(void* const* d_in, const int* in_sizes, int n_in,
                              void* d_out, int out_size, void* d_ws, size_t ws_size,
                              hipStream_t stream) {
    const float* inputs   = (const float*)d_in[0];   // [B, M, C]
    const float* codebook = (const float*)d_in[1];   // [M, N, C]
    float* out_codes = (float*)d_out;                        // [B, M, C]
    float* out_idx   = (float*)d_out + (size_t)BQ * MQ * CQ; // [B, M]
    (void)d_ws; (void)ws_size;

    fq_fused_kernel<<<dim3(BQ / RPB, MQ), 512, 0, stream>>>(
        inputs, codebook, out_codes, out_idx);
}

// Round 8
// 104.985 us; speedup vs baseline: 1.0829x; 1.0829x over previous
//
#include <hip/hip_runtime.h>
#include <hip/hip_bf16.h>
#include <float.h>

// FactoredQuantizer: B=8192, M=16, N=256, C=64
// inputs  [B, M, C] fp32;  codebook [M, N, C] fp32
// out = codes [B, M, C] fp32 ++ idx [B, M] (as fp32 values)
//
// Round 17: combine r15's occupancy (16 waves/CU, 4/SIMD, free-running,
// ONE barrier) with r16's B-reuse (2 row-tiles share every B batch).
// r15 vs r16 isolated the regime: free-running waves/SIMD 4->2 cost +56%
// even with half the DS reads -> keep 16 waves AND halve DS reads.
// Register fix that makes rt=2 fit at 4 waves/SIMD (128-reg cap):
//   - code QUARTER passes (4 x 64 codes): acc[2][4] = 32 regs (was 64)
//   - per-lane argmin carry across passes; 4-level lane tree ONCE at end
//     (also cuts argmin shuffles 4x -> less DS-pipe pressure)
// Hot-loop live set ~= acc32 + afr48 + bfr8 + carry16 + c2r4 + addr ~12
// = ~120 <= 128. Per-wave ds_read_b128: 192 -> 96 (CU: 3072 -> 1536).
// s_setprio(1) around MFMA bursts (T5: free-running = role diversity).
// Per-acc MFMA chain order (h,j,i), c2 summation order, and tie rules
// unchanged -> bit-identical output vs the passing kernels.

#define BQ 8192
#define MQ 16
#define NQ 256
#define CQ 64
#define RPB 512       // rows per block (16 waves x 32 rows)

typedef short  shortx8 __attribute__((ext_vector_type(8)));
typedef float  f32x4   __attribute__((ext_vector_type(4)));

#define HI_MASK 0xffff0000u

// Truncation 3-split of two floats a,b packed into three dwords
// (low short = a's bf16, high short = b's bf16). Exact: a0+a1+a2 == a.
__device__ __forceinline__ void split3_pair(float a, float b,
                                            uint& q0, uint& q1, uint& q2) {
    const uint ba = __builtin_bit_cast(uint, a);
    const uint bb = __builtin_bit_cast(uint, b);
    q0 = (ba >> 16) | (bb & HI_MASK);
    const float r1a = a - __builtin_bit_cast(float, ba & HI_MASK);
    const float r1b = b - __builtin_bit_cast(float, bb & HI_MASK);
    const uint c1a = __builtin_bit_cast(uint, r1a);
    const uint c1b = __builtin_bit_cast(uint, r1b);
    q1 = (c1a >> 16) | (c1b & HI_MASK);
    const float r2a = r1a - __builtin_bit_cast(float, c1a & HI_MASK);
    const float r2b = r1b - __builtin_bit_cast(float, c1b & HI_MASK);
    q2 = (__builtin_bit_cast(uint, r2a) >> 16) |
         (__builtin_bit_cast(uint, r2b) & HI_MASK);
}

// ---------------------------------------------------------------------------
// Fused kernel. Grid (16,16) = 256 blocks = 1/CU; block = 1024 threads
// (16 waves, 4/SIMD). Phase 1 (once): transcode this m's codebook slice
// into LDS bf16x3 fragments (96 KB, layout as rounds 14-16) + c2 (prep's
// exact summation order). ONE __syncthreads. Phase 2: wave w free-runs over
// rows [rowB + w*32, +32) = 2 row-tiles of 16 rows sharing every B batch,
// sweeping codes in 4 quarter-passes of 64.
// ---------------------------------------------------------------------------
__global__ __launch_bounds__(1024, 4) void fq_fused_kernel(
        const float* __restrict__ inputs,
        const float* __restrict__ codebook,
        float* __restrict__ out_codes,
        float* __restrict__ out_idx) {
    const int m    = blockIdx.y;
    const int rowB = blockIdx.x * RPB;
    const int w    = (int)threadIdx.x >> 6;
    const int lane = (int)threadIdx.x & 63;
    const int quad = lane >> 4;
    const int col  = lane & 15;

    __shared__ unsigned short lds_b[96 * 512];   // 96 KB: 96 frags x 64 lanes x 8
    __shared__ float s_c2v[NQ];

    // ---- transcode codebook slice into LDS fragments + c2 (once) ----
    // item (n, kc): n = item>>3, kc = item&7 (kc == lane&7 -> the 8-lane
    // shfl tree reproduces the original prep kernel's c2 order exactly).
    const float* cbm = codebook + (size_t)m * NQ * CQ;
    #pragma unroll
    for (int it = 0; it < 2; ++it) {
        const int item = (int)threadIdx.x + it * 1024;
        const int kc = item & 7;
        const int n  = item >> 3;
        const int nt = n >> 4, cc = n & 15;
        const int h = kc >> 2, q = kc & 3;
        const float* src = cbm + (size_t)n * CQ + kc * 8;
        const float4 va = *(const float4*)src;
        const float4 vb = *(const float4*)(src + 4);
        const float el[8] = {va.x, va.y, va.z, va.w, vb.x, vb.y, vb.z, vb.w};

        float s = 0.0f;
        #pragma unroll
        for (int u = 0; u < 8; ++u) s = fmaf(el[u], el[u], s);
        s += __shfl_xor(s, 1, 64);
        s += __shfl_xor(s, 2, 64);
        s += __shfl_xor(s, 4, 64);
        if (kc == 0) s_c2v[n] = s;

        uint p0[4], p1[4], p2[4];
        #pragma unroll
        for (int u = 0; u < 4; ++u)
            split3_pair(el[2 * u], el[2 * u + 1], p0[u], p1[u], p2[u]);
        const int lf = q * 16 + cc;
        #pragma unroll
        for (int j = 0; j < 3; ++j) {
            const uint* p = (j == 0) ? p0 : (j == 1) ? p1 : p2;
            unsigned short* dst =
                &lds_b[(((j << 1) + h) * 16 + nt) * 512 + lf * 8];
            *(uint4*)dst = make_uint4(p[0], p[1], p[2], p[3]);
        }
    }
    __syncthreads();   // the ONLY barrier: B fragments + c2 ready

    // ---- free-running per-wave main: 32 rows (2 rt) x 256 codes ----
    const int row0 = rowB + w * 32;

    // A-fragments for BOTH row-tiles: direct per-lane global reads.
    // Lane (quad,col) reads x[row0+rt*16+col][h*32+quad*8 .. +8]; the 8
    // lanes sharing a row jointly consume the full 256B row -> every 64B
    // line fully used, no fetch amplification.
    shortx8 afr[3][2][2];   // [i][rt][h]
    #pragma unroll
    for (int rt = 0; rt < 2; ++rt) {
        const float* xb =
            inputs + ((size_t)(row0 + rt * 16 + col) * MQ + m) * CQ;
        #pragma unroll
        for (int h = 0; h < 2; ++h) {
            const float4 va = *(const float4*)(xb + h * 32 + quad * 8);
            const float4 vb = *(const float4*)(xb + h * 32 + quad * 8 + 4);
            const float el[8] = {va.x, va.y, va.z, va.w,
                                 vb.x, vb.y, vb.z, vb.w};
            uint q0[4], q1[4], q2[4];
            #pragma unroll
            for (int u = 0; u < 4; ++u)
                split3_pair(el[2 * u], el[2 * u + 1], q0[u], q1[u], q2[u]);
            afr[0][rt][h] = __builtin_bit_cast(shortx8,
                make_uint4(q0[0], q0[1], q0[2], q0[3]));
            afr[1][rt][h] = __builtin_bit_cast(shortx8,
                make_uint4(q1[0], q1[1], q1[2], q1[3]));
            afr[2][rt][h] = __builtin_bit_cast(shortx8,
                make_uint4(q2[0], q2[1], q2[2], q2[3]));
        }
    }

    // per-lane argmin carry (candidates ascend in n -> strict < keeps
    // the lowest n on ties)
    float bdc[2][4]; int bic[2][4];
    #pragma unroll
    for (int rt = 0; rt < 2; ++rt)
        #pragma unroll
        for (int reg = 0; reg < 4; ++reg) { bdc[rt][reg] = FLT_MAX; bic[rt][reg] = 0; }

    // ---- 4 code-quarter passes: 64 codes each ----
    #pragma unroll 1
    for (int cq = 0; cq < 4; ++cq) {
        float c2r[4];
        #pragma unroll
        for (int nt = 0; nt < 4; ++nt)
            c2r[nt] = s_c2v[cq * 64 + nt * 16 + col];

        f32x4 acc[2][4];
        #pragma unroll
        for (int rt = 0; rt < 2; ++rt)
            #pragma unroll
            for (int nt = 0; nt < 4; ++nt)
                acc[rt][nt] = (f32x4){0.f, 0.f, 0.f, 0.f};

        // hot loop: each B batch (4 ds_read_b128) feeds BOTH row-tiles
        #pragma unroll
        for (int h = 0; h < 2; ++h) {
            #pragma unroll
            for (int j = 0; j < 3; ++j) {
                shortx8 bfr[4];
                #pragma unroll
                for (int nt = 0; nt < 4; ++nt)
                    bfr[nt] = *(const shortx8*)
                        &lds_b[(((j << 1) + h) * 16 + cq * 4 + nt) * 512
                               + lane * 8];
                __builtin_amdgcn_s_setprio(1);
                #pragma unroll
                for (int i = 0; i <= 2 - j; ++i) {
                    #pragma unroll
                    for (int nt = 0; nt < 4; ++nt) {
                        acc[0][nt] = __builtin_amdgcn_mfma_f32_16x16x32_bf16(
                            afr[i][0][h], bfr[nt], acc[0][nt], 0, 0, 0);
                        acc[1][nt] = __builtin_amdgcn_mfma_f32_16x16x32_bf16(
                            afr[i][1][h], bfr[nt], acc[1][nt], 0, 0, 0);
                    }
                }
                __builtin_amdgcn_s_setprio(0);
            }
        }

        // per-lane local argmin update (no shuffles here)
        #pragma unroll
        for (int rt = 0; rt < 2; ++rt)
            #pragma unroll
            for (int reg = 0; reg < 4; ++reg)
                #pragma unroll
                for (int nt = 0; nt < 4; ++nt) {
                    const float d = fmaf(-2.0f, acc[rt][nt][reg], c2r[nt]);
                    if (d < bdc[rt][reg]) {
                        bdc[rt][reg] = d;
                        bic[rt][reg] = cq * 64 + nt * 16 + col;
                    }
                }
    }

    // ---- final argmin: 4-level tree over the 16 col lanes (once) ----
    #pragma unroll
    for (int rt = 0; rt < 2; ++rt)
        #pragma unroll
        for (int reg = 0; reg < 4; ++reg) {
            float bd = bdc[rt][reg]; int bi = bic[rt][reg];
            #pragma unroll
            for (int mask = 1; mask <= 8; mask <<= 1) {
                const float od = __shfl_xor(bd, mask, 64);
                const int   oi = __shfl_xor(bi, mask, 64);
                if (od < bd || (od == bd && oi < bi)) { bd = od; bi = oi; }
            }
            bdc[rt][reg] = bd; bic[rt][reg] = bi;
        }

    // idx write: lane (quad, col==0) owns rows rt*16 + quad*4 + reg
    if (col == 0) {
        #pragma unroll
        for (int rt = 0; rt < 2; ++rt)
            #pragma unroll
            for (int reg = 0; reg < 4; ++reg)
                out_idx[(size_t)(row0 + rt * 16 + quad * 4 + reg) * MQ + m] =
                    (float)bic[rt][reg];
    }

    // gather codes: row jj's winner lives on lane ((jj&15)>>2)*16, reg jj&3
    // of tile jj>>4; lane = element (256B stores)
    #pragma unroll
    for (int jj = 0; jj < 32; ++jj) {
        const int rt  = jj >> 4;
        const int r16 = jj & 15;
        const int bn  = __shfl(bic[rt][r16 & 3], (r16 >> 2) * 16, 64);
        out_codes[((size_t)(row0 + jj) * MQ + m) * CQ + lane] =
            cbm[(size_t)bn * CQ + lane];
    }
}

extern "C" void kernel_launch(void* const* d_in, const int* in_sizes, int n_in,
                              void* d_out, int out_size, void* d_ws, size_t ws_size,
                              hipStream_t stream) {
    const float* inputs   = (const float*)d_in[0];   // [B, M, C]
    const float* codebook = (const float*)d_in[1];   // [M, N, C]
    float* out_codes = (float*)d_out;                        // [B, M, C]
    float* out_idx   = (float*)d_out + (size_t)BQ * MQ * CQ; // [B, M]
    (void)d_ws; (void)ws_size;

    fq_fused_kernel<<<dim3(BQ / RPB, MQ), 1024, 0, stream>>>(
        inputs, codebook, out_codes, out_idx);
}